// Round 8
// baseline (421.505 us; speedup 1.0000x reference)
//
#include <hip/hip_runtime.h>
#include <stdint.h>

#define SLEN   2048
#define DMODEL 1024
#define NHEAD  16
#define DKH    64
#define BATCH  4

typedef unsigned short ushort_t;
typedef __bf16         bf16x8 __attribute__((ext_vector_type(8)));
typedef unsigned short u16x8  __attribute__((ext_vector_type(8)));
typedef unsigned short u16x4  __attribute__((ext_vector_type(4)));
typedef unsigned int   u32x4  __attribute__((ext_vector_type(4)));
typedef float          f32x4  __attribute__((ext_vector_type(4)));

// log2(e)/8: folded into the Q projection so flash computes p = exp2(s) raw.
#define QSCALE 0.18033688f

__device__ __forceinline__ ushort_t f2bf(float f) {
  unsigned int u = __builtin_bit_cast(unsigned int, f);
  u += 0x7fffu + ((u >> 16) & 1u);   // RNE
  return (ushort_t)(u >> 16);
}
// pack two fp32 -> two bf16 (round-half-away) in one v_perm: low=bf16(a)
__device__ __forceinline__ unsigned pk2(float a, float b) {
  const unsigned ua = __builtin_bit_cast(unsigned, a) + 0x8000u;
  const unsigned ub = __builtin_bit_cast(unsigned, b) + 0x8000u;
  return __builtin_amdgcn_perm(ub, ua, 0x07060302u);
}
__device__ __forceinline__ u16x8 cvt8f(const float* p) {
  f32x4 a = *(const f32x4*)p;
  f32x4 b = *(const f32x4*)(p + 4);
  u32x4 w;
  w[0] = pk2(a[0], a[1]);
  w[1] = pk2(a[2], a[3]);
  w[2] = pk2(b[0], b[1]);
  w[3] = pk2(b[2], b[3]);
  return __builtin_bit_cast(u16x8, w);
}

typedef __attribute__((address_space(1))) void gvoid_t;
typedef __attribute__((address_space(3))) void lvoid_t;
__device__ __forceinline__ void gld_lds16(const void* g, void* l) {
  __builtin_amdgcn_global_load_lds((gvoid_t*)(g), (lvoid_t*)(l), 16, 0, 0);
}

// XOR-swizzled flat index into a 64x64 u16 tile (flash staging)
__device__ __forceinline__ int swz(int row, int c) {
  return row * 64 + (c ^ ((row & 7) * 8));
}

// ---------------------------------------------------------------------------
// Convert Wq,Wk,Wv,Wo (4 x 1M) and q,k,v (3 x 8M) fp32 -> bf16.
// ---------------------------------------------------------------------------
__global__ __launch_bounds__(256) void cvt_all(
    const float* __restrict__ Wq, const float* __restrict__ Wk,
    const float* __restrict__ Wv, const float* __restrict__ Wo,
    const float* __restrict__ q, const float* __restrict__ k,
    const float* __restrict__ v,
    ushort_t* __restrict__ Wbf, ushort_t* __restrict__ Xq,
    ushort_t* __restrict__ Xk,  ushort_t* __restrict__ Xv) {
  const int b = blockIdx.x;
  if (b < 2048) {                                   // weights: 4M elems
    const int gid = b * 256 + threadIdx.x;          // 0..524287
    const int seg = gid >> 17;
    const int off = (gid & 131071) * 8;
    const float* src = (seg == 0) ? Wq : (seg == 1) ? Wk : (seg == 2) ? Wv : Wo;
    *(u16x8*)&Wbf[((size_t)seg << 20) + off] = cvt8f(src + off);
  } else {                                          // activations: 3 x 8M elems
    const int gid = (b - 2048) * 256 + threadIdx.x; // 0..3145727
    const int seg = gid >> 20;
    const size_t off = (size_t)(gid & 1048575) * 8;
    const float* src = (seg == 0) ? q : (seg == 1) ? k : v;
    ushort_t*    dst = (seg == 0) ? Xq : (seg == 1) ? Xk : Xv;
    *(u16x8*)&dst[off] = cvt8f(src + off);
  }
}

// ---------------------------------------------------------------------------
// GEMM: Out[m,n] = sum_k X[m,k]*W[n,k] + bias[n].  X and W both bf16.
// ROUND 8: back to the measured-best r3 structure (128x256 tile, BK=32,
// 4 waves, double-buffered DMA staging, STAGE-first + vmcnt(6) + 2 raw
// barriers per K-step, 48 KB LDS -> 3 blocks/CU), plus the two r7-proven
// fixes grafted on:
//  (1) TRUE conflict-free LDS swizzle: 16B-chunk ^= (row>>1)&3 on both the
//      pre-swizzled global staging source and the fragment reads (r7
//      measured SQ_LDS_BANK_CONFLICT 4.7M -> 0 with this exact formula).
//  (2) mode-1 epilogue via grouped LDS transpose -> coalesced u16x8 stores
//      (kills the 2x HBM write amplification of scalar 2B @128B-stride).
// mode 1: bf16 head-split [B,H,S,DK] (scale folded); mode 2: bf16
// [B,H,DK,S]; mode 0: fp32 plain [M,N].
// ---------------------------------------------------------------------------
__device__ __forceinline__ void gemm_body(
    const ushort_t* __restrict__ X, const ushort_t* __restrict__ W,
    const float* __restrict__ bias, void* __restrict__ Outv, const int mode,
    const float sc)
{
  __shared__ ushort_t lA[2][128 * 32];   // 2 x 8 KB
  __shared__ ushort_t lB[2][256 * 32];   // 2 x 16 KB   (48 KB total)

  const int t    = threadIdx.x;
  const int lane = t & 63;
  const int w    = t >> 6;
  const int wm   = (w >> 1) * 64;
  const int wn   = (w & 1) * 128;
  const int m0   = blockIdx.x * 128;
  const int n0   = blockIdx.y * 256;
  const int col  = lane & 15;
  const int quad = lane >> 4;

  f32x4 acc[4][8];
#pragma unroll
  for (int i = 0; i < 4; i++)
#pragma unroll
    for (int j = 0; j < 8; j++) acc[i][j] = f32x4{0.f, 0.f, 0.f, 0.f};

  // staging: thread t covers row rA = t>>2 (of each 64-row group), 16B chunk
  // t&3, source pre-swizzled: LDS[r][c] holds global chunk c ^ ((r>>1)&3).
  // Rows +64/+128/+192 share the XOR ( ((r+64)>>1)&3 == (r>>1)&3 ).
  const int rA   = t >> 2;
  const int csrc = ((t & 3) ^ ((rA >> 1) & 3)) * 8;
  const ushort_t* gA0 = X + (size_t)(m0 + rA) * DMODEL + csrc;
  const ushort_t* gA1 = gA0 + (size_t)64 * DMODEL;
  const ushort_t* gB0 = W + (size_t)(n0 + rA) * DMODEL + csrc;
  const ushort_t* gB1 = gB0 + (size_t)64 * DMODEL;
  const ushort_t* gB2 = gB0 + (size_t)128 * DMODEL;
  const ushort_t* gB3 = gB0 + (size_t)192 * DMODEL;

#define STAGE_G(buf, k0) do {                        \
    gld_lds16(gB0 + (k0), &lB[buf][t * 8]);          \
    gld_lds16(gB1 + (k0), &lB[buf][t * 8 + 2048]);   \
    gld_lds16(gB2 + (k0), &lB[buf][t * 8 + 4096]);   \
    gld_lds16(gB3 + (k0), &lB[buf][t * 8 + 6144]);   \
    gld_lds16(gA0 + (k0), &lA[buf][t * 8]);          \
    gld_lds16(gA1 + (k0), &lA[buf][t * 8 + 2048]);   \
  } while (0)

  // fragment-read swizzle: fragment row = 16*m' + col (m' any), so
  // (row>>1)&3 == (col>>1)&3 for every fragment this thread touches.
  const int rchunk = (quad ^ ((col >> 1) & 3)) * 8;

  STAGE_G(0, 0);   // prologue: tile 0 -> buffer 0

  const int NT = DMODEL / 32;   // 32 K-steps
  for (int ks = 0; ks < NT; ++ks) {
    const int cur = ks & 1;
    if (ks + 1 < NT) {
      STAGE_G(cur ^ 1, (ks + 1) * 32);               // prefetch next tile
      asm volatile("s_waitcnt vmcnt(6)" ::: "memory"); // cur tile landed,
    } else {                                           // next 6 stay in flight
      asm volatile("s_waitcnt vmcnt(0)" ::: "memory");
    }
    __builtin_amdgcn_s_barrier();
    __builtin_amdgcn_sched_barrier(0);

    bf16x8 af[4], bfr[8];
#pragma unroll
    for (int mi = 0; mi < 4; mi++)
      af[mi] = __builtin_bit_cast(bf16x8,
          *(const u16x8*)&lA[cur][(wm + mi * 16 + col) * 32 + rchunk]);
#pragma unroll
    for (int ni = 0; ni < 8; ni++)
      bfr[ni] = __builtin_bit_cast(bf16x8,
          *(const u16x8*)&lB[cur][(wn + ni * 16 + col) * 32 + rchunk]);

#pragma unroll
    for (int mi = 0; mi < 4; mi++)
#pragma unroll
      for (int ni = 0; ni < 8; ni++)
        acc[mi][ni] = __builtin_amdgcn_mfma_f32_16x16x32_bf16(
            af[mi], bfr[ni], acc[mi][ni], 0, 0, 0);

    __builtin_amdgcn_s_barrier();        // all reads of buf[cur] done before
    __builtin_amdgcn_sched_barrier(0);   // next iter DMA-writes into it
  }
#undef STAGE_G

  const int b_ = (m0 + wm) >> 11;   // block never straddles a batch boundary

  if (mode == 1) {
    // Grouped LDS transpose: 8 groups of 16 m-rows. Scratch = lB[0]
    // (16 rows x 264 u16 = 4224 u16 <= 8192; stride 264 -> 528 B, 16B
    // aligned, 132 dw % 8 != 0 so quad rows spread banks).
    ushort_t* tb = &lB[0][0];
    float bns_[8];
#pragma unroll
    for (int ni = 0; ni < 8; ni++)
      bns_[ni] = bias[n0 + wn + ni * 16 + col] * sc;
    const int h0 = n0 >> 6;
    for (int g = 0; g < 8; ++g) {
      __syncthreads();
      if ((w >> 1) == (g >> 2)) {        // the 2 waves owning these 16 rows
        const int mi = g & 3;
#pragma unroll
        for (int ni = 0; ni < 8; ni++)
#pragma unroll
          for (int r = 0; r < 4; r++)
            tb[(quad * 4 + r) * 264 + wn + ni * 16 + col] =
                f2bf(fmaf(acc[mi][ni][r], sc, bns_[ni]));
      }
      __syncthreads();
      const int sg = (m0 & (SLEN - 1)) + g * 16;
#pragma unroll
      for (int j = 0; j < 2; ++j) {      // 16 rows x 256 u16, 8 rows/iter
        const int rr = j * 8 + (t >> 5);
        const int ch = t & 31;           // 32 chunks of 8 u16 per row
        u16x8 vv = *(const u16x8*)&tb[rr * 264 + ch * 8];
        const int h  = h0 + (ch >> 3);
        const int dk = (ch & 7) * 8;
        *(u16x8*)&((ushort_t*)Outv)[(((size_t)(b_ * NHEAD + h)) * SLEN +
                                     (sg + rr)) * DKH + dk] = vv;
      }
    }
    return;
  }

#pragma unroll
  for (int ni = 0; ni < 8; ni++) {
    const int n  = n0 + wn + ni * 16 + col;
    const float bn = bias[n];
    const int h  = n >> 6, dk = n & (DKH - 1);
#pragma unroll
    for (int mi = 0; mi < 4; mi++) {
      if (mode == 2) {
        const int s0 = ((m0 + wm + mi * 16 + quad * 4) & (SLEN - 1));
        u16x4 pk;
#pragma unroll
        for (int r = 0; r < 4; r++) pk[r] = f2bf(acc[mi][ni][r] + bn);
        *(u16x4*)&((ushort_t*)Outv)[(((size_t)(b_ * NHEAD + h)) * DKH + dk) * SLEN + s0] = pk;
      } else {
#pragma unroll
        for (int r = 0; r < 4; r++) {
          const int m = m0 + wm + mi * 16 + quad * 4 + r;
          ((float*)Outv)[(size_t)m * DMODEL + n] = acc[mi][ni][r] + bn;
        }
      }
    }
  }
}

// fused Q/K/V projections (X = bf16 workspace, W = bf16 workspace)
__global__ __launch_bounds__(256) void gemm_qkv(
    const ushort_t* Xq, const ushort_t* Xk, const ushort_t* Xv,
    const ushort_t* Wbf,
    const float* bq, const float* bk, const float* bv,
    ushort_t* Qh, ushort_t* Kh, ushort_t* VhT) {
  const int z = blockIdx.z;
  const ushort_t* X = (z == 0) ? Xq : (z == 1) ? Xk : Xv;
  const ushort_t* W = Wbf + ((size_t)z << 20);
  const float* bias = (z == 0) ? bq : (z == 1) ? bk : bv;
  ushort_t* out     = (z == 0) ? Qh : (z == 1) ? Kh : VhT;
  gemm_body(X, W, bias, out, (z == 2) ? 2 : 1, (z == 0) ? QSCALE : 1.0f);
}

__global__ __launch_bounds__(256) void gemm_out(
    const ushort_t* X, const ushort_t* Wobf, const float* bo, float* Out) {
  gemm_body(X, Wobf, bo, Out, 0, 1.0f);
}

// ---------------------------------------------------------------------------
// Flash attention, causal. Paired q-blocks (x, 31-x): every workgroup does
// exactly 33 tile-computes (uniform load) and stages each K/V tile ONCE for
// the pair. Grid (16, 64) = 1024 blocks = 4/CU. Q pre-scaled by log2(e)/8
// in the projection; p = exp2(s) with no offset (constant factor cancels
// between PV numerator and row-sum denominator).
// ---------------------------------------------------------------------------
__global__ __launch_bounds__(256, 4) void flash_attn(
    const ushort_t* __restrict__ Qh, const ushort_t* __restrict__ Kh,
    const ushort_t* __restrict__ VhT, ushort_t* __restrict__ Out)
{
  __shared__ ushort_t lK[2 * 64 * 64];   // 16 KB (double-buffered)
  __shared__ ushort_t lV[2 * 64 * 64];   // 16 KB (double-buffered)
  __shared__ ushort_t lP[4 * 16 * 64];   //  8 KB

  const int t    = threadIdx.x;
  const int lane = t & 63;
  const int w    = t >> 6;
  const int col  = lane & 15;
  const int quad = lane >> 4;
  const int bh   = blockIdx.y;
  const int x    = blockIdx.x;          // 0..15
  const int ntA  = x + 1;               // tiles for q-block A
  const int ntB  = 32 - x;              // tiles for q-block B  (ntB > ntA)
  const int q0A  = x * 64;
  const int q0B  = (31 - x) * 64;

  const ushort_t* Qb = Qh  + (size_t)bh * SLEN * DKH;
  const ushort_t* Kb = Kh  + (size_t)bh * SLEN * DKH;
  const ushort_t* Vt = VhT + (size_t)bh * DKH * SLEN;

  bf16x8 qfA[2], qfB[2];
  {
    const int ra = q0A + w * 16 + col;
    const int rb = q0B + w * 16 + col;
    qfA[0] = __builtin_bit_cast(bf16x8, *(const u16x8*)&Qb[(size_t)ra * DKH + quad * 8]);
    qfA[1] = __builtin_bit_cast(bf16x8, *(const u16x8*)&Qb[(size_t)ra * DKH + 32 + quad * 8]);
    qfB[0] = __builtin_bit_cast(bf16x8, *(const u16x8*)&Qb[(size_t)rb * DKH + quad * 8]);
    qfB[1] = __builtin_bit_cast(bf16x8, *(const u16x8*)&Qb[(size_t)rb * DKH + 32 + quad * 8]);
  }

  f32x4 accA[4], accB[4], laccA, laccB;
#pragma unroll
  for (int n2 = 0; n2 < 4; n2++) {
    accA[n2] = f32x4{0.f, 0.f, 0.f, 0.f};
    accB[n2] = f32x4{0.f, 0.f, 0.f, 0.f};
  }
  laccA = f32x4{0.f, 0.f, 0.f, 0.f};
  laccB = f32x4{0.f, 0.f, 0.f, 0.f};

  u16x8 ones_u;
#pragma unroll
  for (int i = 0; i < 8; ++i) ones_u[i] = 0x3F80;  // bf16 1.0
  const bf16x8 onesf = __builtin_bit_cast(bf16x8, ones_u);

  const int fA   = t * 8;
  const int rowA = fA >> 6;
  const int innA = fA & 63;
  const int cA   = innA ^ ((rowA & 7) * 8);
  const int rowB = rowA + 32;
  const int cB   = innA ^ ((rowB & 7) * 8);
  const ushort_t* gK0 = Kb + (size_t)rowA * DKH + cA;
  const ushort_t* gK1 = Kb + (size_t)rowB * DKH + cB;
  const ushort_t* gV0 = Vt + (size_t)rowA * SLEN + cA;
  const ushort_t* gV1 = Vt + (size_t)rowB * SLEN + cB;
  ushort_t* sK0 = &lK[fA];
  ushort_t* sK1 = &lK[fA + 2048];
  ushort_t* sV0 = &lV[fA];
  ushort_t* sV1 = &lV[fA + 2048];

  ushort_t* lPw = &lP[w * 1024];

  // one tile-compute for one q-block: QK^T -> exp2 -> P (LDS) -> PV
  auto compute = [&](const bf16x8* qf, f32x4* acc_o, f32x4& lacc,
                     const int q0, const bool diag, const int kb,
                     const ushort_t* Kc, const ushort_t* Vc) {
    f32x4 sacc[4];
#pragma unroll
    for (int nt = 0; nt < 4; nt++) sacc[nt] = f32x4{0.f, 0.f, 0.f, 0.f};
#pragma unroll
    for (int ks = 0; ks < 2; ++ks) {
#pragma unroll
      for (int nt = 0; nt < 4; ++nt) {
        bf16x8 kf = __builtin_bit_cast(bf16x8,
            *(const u16x8*)&Kc[swz(nt * 16 + col, ks * 32 + quad * 8)]);
        sacc[nt] = __builtin_amdgcn_mfma_f32_16x16x32_bf16(qf[ks], kf, sacc[nt], 0, 0, 0);
      }
    }
#pragma unroll
    for (int r = 0; r < 4; r++) {
#pragma unroll
      for (int nt = 0; nt < 4; nt++) {
        float p = exp2f(sacc[nt][r]);
        if (diag) {
          const int kg = kb + nt * 16 + col;
          const int qg = q0 + w * 16 + quad * 4 + r;
          if (kg > qg) p = 0.f;
        }
        lPw[swz(quad * 4 + r, nt * 16 + col)] = f2bf(p);
      }
    }
    asm volatile("s_waitcnt lgkmcnt(0)" ::: "memory");
#pragma unroll
    for (int ks = 0; ks < 2; ++ks) {
      bf16x8 pf = __builtin_bit_cast(bf16x8,
          *(const u16x8*)&lPw[swz(col, ks * 32 + quad * 8)]);
      lacc = __builtin_amdgcn_mfma_f32_16x16x32_bf16(pf, onesf, lacc, 0, 0, 0);
#pragma unroll
      for (int n2 = 0; n2 < 4; ++n2) {
        bf16x8 vf = __builtin_bit_cast(bf16x8,
            *(const u16x8*)&Vc[swz(n2 * 16 + col, ks * 32 + quad * 8)]);
        acc_o[n2] = __builtin_amdgcn_mfma_f32_16x16x32_bf16(pf, vf, acc_o[n2], 0, 0, 0);
      }
    }
  };

  // prologue: stage tile 0 into buffer 0
  gld_lds16(gK0, sK0);
  gld_lds16(gK1, sK1);
  gld_lds16(gV0, sV0);
  gld_lds16(gV1, sV1);

  for (int it = 0; it < ntB; ++it) {
    const int cur = it & 1;
    const int kb  = it * 64;
    const ushort_t* Kc = &lK[cur * 4096];
    const ushort_t* Vc = &lV[cur * 4096];

    if (it + 1 < ntB) {
      const size_t kb1 = (size_t)(it + 1) * 64;
      const int nb = (cur ^ 1) * 4096;
      gld_lds16(gK0 + kb1 * DKH, sK0 + nb);
      gld_lds16(gK1 + kb1 * DKH, sK1 + nb);
      gld_lds16(gV0 + kb1,       sV0 + nb);
      gld_lds16(gV1 + kb1,       sV1 + nb);
      asm volatile("s_waitcnt vmcnt(4)" ::: "memory");
    } else {
      asm volatile("s_waitcnt vmcnt(0)" ::: "memory");
    }
    __builtin_amdgcn_s_barrier();   // current buffer fully landed, all waves

    compute(qfB, accB, laccB, q0B, it == ntB - 1, kb, Kc, Vc);
    if (it < ntA)
      compute(qfA, accA, laccA, q0A, it == ntA - 1, kb, Kc, Vc);

    __builtin_amdgcn_s_barrier();   // reads of buf[cur] done before re-stage
  }

  const int b_ = bh >> 4;
  const int h  = bh & (NHEAD - 1);
#pragma unroll
  for (int side = 0; side < 2; ++side) {
    const f32x4* ao = side ? accA : accB;
    const f32x4& la = side ? laccA : laccB;
    const int q0 = side ? q0A : q0B;
#pragma unroll
    for (int r = 0; r < 4; r++) {
      const int qg = q0 + w * 16 + quad * 4 + r;
      const float inv = 1.f / la[r];
#pragma unroll
      for (int n2 = 0; n2 < 4; n2++) {
        const size_t oidx = ((size_t)b_ * SLEN + qg) * DMODEL + h * DKH + n2 * 16 + col;
        Out[oidx] = f2bf(ao[n2][r] * inv);
      }
    }
  }
}

// ---------------------------------------------------------------------------
extern "C" void kernel_launch(void* const* d_in, const int* in_sizes, int n_in,
                              void* d_out, int out_size, void* d_ws, size_t ws_size,
                              hipStream_t stream) {
  (void)in_sizes; (void)n_in; (void)out_size; (void)ws_size;
  const float* q  = (const float*)d_in[0];
  const float* k  = (const float*)d_in[1];
  const float* v  = (const float*)d_in[2];
  const float* Wq = (const float*)d_in[3];
  const float* bq = (const float*)d_in[4];
  const float* Wk = (const float*)d_in[5];
  const float* bk = (const float*)d_in[6];
  const float* Wv = (const float*)d_in[7];
  const float* bv = (const float*)d_in[8];
  const float* Wo = (const float*)d_in[9];
  const float* bo = (const float*)d_in[10];
  // d_in[11] = causal mask (applied analytically)

  ushort_t* ws = (ushort_t*)d_ws;
  const size_t NELEM = (size_t)BATCH * SLEN * DMODEL;   // 8M elems
  ushort_t* Wbf = ws;                        // 4 x 1M bf16 (Wq,Wk,Wv,Wo)  8 MB
  ushort_t* Qh  = ws + 4 * (1u << 20);       // [B,H,S,DK] bf16           16 MB
  ushort_t* Kh  = Qh + NELEM;                // [B,H,S,DK] bf16           16 MB
  ushort_t* Xq  = Kh + NELEM;                // [B,S,D] bf16 (q)          16 MB
  ushort_t* Xk  = Xq + NELEM;                // [B,S,D] bf16 (k)          16 MB
  ushort_t* Ao  = Xq;                        // aliases Xq (dead after qkv)
  ushort_t* VhT = (ushort_t*)d_out;          // [B,H,DK,S] bf16 in d_out lo half
  ushort_t* Xv  = (ushort_t*)d_out + NELEM;  // [B,S,D] bf16 (v) in d_out hi half
                                             // (both dead before gemm_out writes)

  hipLaunchKernelGGL(cvt_all, dim3(2048 + 12288), dim3(256), 0, stream,
                     Wq, Wk, Wv, Wo, q, k, v, Wbf, Xq, Xk, Xv);
  hipLaunchKernelGGL(gemm_qkv, dim3(64, 4, 3), dim3(256), 0, stream,
                     Xq, Xk, Xv, Wbf, bq, bk, bv, Qh, Kh, VhT);
  hipLaunchKernelGGL(flash_attn, dim3(16, BATCH * NHEAD), dim3(256), 0, stream,
                     Qh, Kh, VhT, Ao);
  hipLaunchKernelGGL(gemm_out, dim3(64, 4), dim3(256), 0, stream,
                     Ao, Wbf + (3u << 20), bo, (float*)d_out);
}

// Round 9
// 384.317 us; speedup vs baseline: 1.0968x; 1.0968x over previous
//
#include <hip/hip_runtime.h>
#include <stdint.h>

#define SLEN   2048
#define DMODEL 1024
#define NHEAD  16
#define DKH    64
#define BATCH  4

typedef unsigned short ushort_t;
typedef __bf16         bf16x8 __attribute__((ext_vector_type(8)));
typedef unsigned short u16x8  __attribute__((ext_vector_type(8)));
typedef unsigned short u16x4  __attribute__((ext_vector_type(4)));
typedef unsigned int   u32x4  __attribute__((ext_vector_type(4)));
typedef float          f32x4  __attribute__((ext_vector_type(4)));

// log2(e)/8: folded into the Q projection so flash computes p = exp2(s) raw.
#define QSCALE 0.18033688f

__device__ __forceinline__ ushort_t f2bf(float f) {
  unsigned int u = __builtin_bit_cast(unsigned int, f);
  u += 0x7fffu + ((u >> 16) & 1u);   // RNE
  return (ushort_t)(u >> 16);
}
// pack two fp32 -> two bf16 (round-half-away) in one v_perm: low=bf16(a)
__device__ __forceinline__ unsigned pk2(float a, float b) {
  const unsigned ua = __builtin_bit_cast(unsigned, a) + 0x8000u;
  const unsigned ub = __builtin_bit_cast(unsigned, b) + 0x8000u;
  return __builtin_amdgcn_perm(ub, ua, 0x07060302u);
}
__device__ __forceinline__ u16x8 cvt8f(const float* p) {
  f32x4 a = *(const f32x4*)p;
  f32x4 b = *(const f32x4*)(p + 4);
  u32x4 w;
  w[0] = pk2(a[0], a[1]);
  w[1] = pk2(a[2], a[3]);
  w[2] = pk2(b[0], b[1]);
  w[3] = pk2(b[2], b[3]);
  return __builtin_bit_cast(u16x8, w);
}

typedef __attribute__((address_space(1))) void gvoid_t;
typedef __attribute__((address_space(3))) void lvoid_t;
__device__ __forceinline__ void gld_lds16(const void* g, void* l) {
  __builtin_amdgcn_global_load_lds((gvoid_t*)(g), (lvoid_t*)(l), 16, 0, 0);
}

// XOR-swizzled flat index into a 64x64 u16 tile (flash staging)
__device__ __forceinline__ int swz(int row, int c) {
  return row * 64 + (c ^ ((row & 7) * 8));
}

// ---------------------------------------------------------------------------
// Convert Wq,Wk,Wv,Wo (4 x 1M) and q,k,v (3 x 8M) fp32 -> bf16.
// ---------------------------------------------------------------------------
__global__ __launch_bounds__(256) void cvt_all(
    const float* __restrict__ Wq, const float* __restrict__ Wk,
    const float* __restrict__ Wv, const float* __restrict__ Wo,
    const float* __restrict__ q, const float* __restrict__ k,
    const float* __restrict__ v,
    ushort_t* __restrict__ Wbf, ushort_t* __restrict__ Xq,
    ushort_t* __restrict__ Xk,  ushort_t* __restrict__ Xv) {
  const int b = blockIdx.x;
  if (b < 2048) {                                   // weights: 4M elems
    const int gid = b * 256 + threadIdx.x;          // 0..524287
    const int seg = gid >> 17;
    const int off = (gid & 131071) * 8;
    const float* src = (seg == 0) ? Wq : (seg == 1) ? Wk : (seg == 2) ? Wv : Wo;
    *(u16x8*)&Wbf[((size_t)seg << 20) + off] = cvt8f(src + off);
  } else {                                          // activations: 3 x 8M elems
    const int gid = (b - 2048) * 256 + threadIdx.x; // 0..3145727
    const int seg = gid >> 20;
    const size_t off = (size_t)(gid & 1048575) * 8;
    const float* src = (seg == 0) ? q : (seg == 1) ? k : v;
    ushort_t*    dst = (seg == 0) ? Xq : (seg == 1) ? Xk : Xv;
    *(u16x8*)&dst[off] = cvt8f(src + off);
  }
}

// ---------------------------------------------------------------------------
// GEMM: Out[m,n] = sum_k X[m,k]*W[n,k] + bias[n].  X and W both bf16.
// ROUND 9: the measured-best r3 structure (128x256 tile, BK=32, 4 waves,
// double-buffered DMA staging, STAGE-first + vmcnt(6) + 2 raw barriers per
// K-step, 48 KB LDS -> 3 blocks/CU) plus the two counter-proven fixes in
// occupancy-neutral form:
//  (1) zero-conflict LDS swizzle: 16B-chunk ^= (row>>1)&3 on staging source
//      AND fragment reads (r7/r8: SQ_LDS_BANK_CONFLICT 4.7M -> 0).
//  (2) mode-1 epilogue: WAVE-LOCAL LDS transpose -> coalesced u16x8 stores.
//      One __syncthreads total; no divergence; acc consumed mi-by-mi in
//      straight-line code so VGPR stays low (r8's barriered version hit
//      192 VGPR -> 2 blocks/CU -> regression). launch_bounds(256,3) caps
//      VGPR at 170 to guarantee 3 blocks/CU.
// mode 1: bf16 head-split [B,H,S,DK] (scale folded); mode 2: bf16
// [B,H,DK,S]; mode 0: fp32 plain [M,N].
// ---------------------------------------------------------------------------
__device__ __forceinline__ void gemm_body(
    const ushort_t* __restrict__ X, const ushort_t* __restrict__ W,
    const float* __restrict__ bias, void* __restrict__ Outv, const int mode,
    const float sc)
{
  __shared__ ushort_t lA[2][128 * 32];   // 2 x 8 KB
  __shared__ ushort_t lB[2][256 * 32];   // 2 x 16 KB   (48 KB total)

  const int t    = threadIdx.x;
  const int lane = t & 63;
  const int w    = t >> 6;
  const int wm   = (w >> 1) * 64;
  const int wn   = (w & 1) * 128;
  const int m0   = blockIdx.x * 128;
  const int n0   = blockIdx.y * 256;
  const int col  = lane & 15;
  const int quad = lane >> 4;

  f32x4 acc[4][8];
#pragma unroll
  for (int i = 0; i < 4; i++)
#pragma unroll
    for (int j = 0; j < 8; j++) acc[i][j] = f32x4{0.f, 0.f, 0.f, 0.f};

  // staging: thread t covers row rA = t>>2 (of each 64-row group), 16B chunk
  // t&3, source pre-swizzled: LDS[r][c] holds global chunk c ^ ((r>>1)&3).
  // Rows +64/+128/+192 share the XOR ( ((r+64)>>1)&3 == (r>>1)&3 ).
  const int rA   = t >> 2;
  const int csrc = ((t & 3) ^ ((rA >> 1) & 3)) * 8;
  const ushort_t* gA0 = X + (size_t)(m0 + rA) * DMODEL + csrc;
  const ushort_t* gA1 = gA0 + (size_t)64 * DMODEL;
  const ushort_t* gB0 = W + (size_t)(n0 + rA) * DMODEL + csrc;
  const ushort_t* gB1 = gB0 + (size_t)64 * DMODEL;
  const ushort_t* gB2 = gB0 + (size_t)128 * DMODEL;
  const ushort_t* gB3 = gB0 + (size_t)192 * DMODEL;

#define STAGE_G(buf, k0) do {                        \
    gld_lds16(gB0 + (k0), &lB[buf][t * 8]);          \
    gld_lds16(gB1 + (k0), &lB[buf][t * 8 + 2048]);   \
    gld_lds16(gB2 + (k0), &lB[buf][t * 8 + 4096]);   \
    gld_lds16(gB3 + (k0), &lB[buf][t * 8 + 6144]);   \
    gld_lds16(gA0 + (k0), &lA[buf][t * 8]);          \
    gld_lds16(gA1 + (k0), &lA[buf][t * 8 + 2048]);   \
  } while (0)

  // fragment-read swizzle: fragment row = 16*m' + col, so
  // (row>>1)&3 == (col>>1)&3 for every fragment this thread touches.
  const int rchunk = (quad ^ ((col >> 1) & 3)) * 8;

  STAGE_G(0, 0);   // prologue: tile 0 -> buffer 0

  const int NT = DMODEL / 32;   // 32 K-steps
  for (int ks = 0; ks < NT; ++ks) {
    const int cur = ks & 1;
    if (ks + 1 < NT) {
      STAGE_G(cur ^ 1, (ks + 1) * 32);               // prefetch next tile
      asm volatile("s_waitcnt vmcnt(6)" ::: "memory"); // cur tile landed,
    } else {                                           // next 6 stay in flight
      asm volatile("s_waitcnt vmcnt(0)" ::: "memory");
    }
    __builtin_amdgcn_s_barrier();
    __builtin_amdgcn_sched_barrier(0);

    bf16x8 af[4], bfr[8];
#pragma unroll
    for (int mi = 0; mi < 4; mi++)
      af[mi] = __builtin_bit_cast(bf16x8,
          *(const u16x8*)&lA[cur][(wm + mi * 16 + col) * 32 + rchunk]);
#pragma unroll
    for (int ni = 0; ni < 8; ni++)
      bfr[ni] = __builtin_bit_cast(bf16x8,
          *(const u16x8*)&lB[cur][(wn + ni * 16 + col) * 32 + rchunk]);

#pragma unroll
    for (int mi = 0; mi < 4; mi++)
#pragma unroll
      for (int ni = 0; ni < 8; ni++)
        acc[mi][ni] = __builtin_amdgcn_mfma_f32_16x16x32_bf16(
            af[mi], bfr[ni], acc[mi][ni], 0, 0, 0);

    __builtin_amdgcn_s_barrier();        // all reads of buf[cur] done before
    __builtin_amdgcn_sched_barrier(0);   // next iter DMA-writes into it
  }
#undef STAGE_G

  const int b_ = (m0 + wm) >> 11;   // block never straddles a batch boundary

  if (mode == 1) {
    // Wave-local LDS transpose -> coalesced u16x8 stores.
    // Each wave transposes its own 64x128 sub-tile through a private
    // 16x136-u16 scratch (4.25 KB, lB flat, disjoint per wave). Within a
    // wave LDS ops execute in order, so no barriers are needed between
    // write->read->overwrite; lgkmcnt(0) orders write vs read.
    __syncthreads();                       // no wave still reads K-loop LDS
    ushort_t* tb = &lB[0][0] + w * 2176;   // 16 x 136 u16 per wave
    float bns_[8];
#pragma unroll
    for (int ni = 0; ni < 8; ni++)
      bns_[ni] = bias[n0 + wn + ni * 16 + col] * sc;
    const int h0 = (n0 + wn) >> 6;
    const int sB = ((m0 + wm) & (SLEN - 1));
#pragma unroll
    for (int mi = 0; mi < 4; mi++) {
#pragma unroll
      for (int ni = 0; ni < 8; ni++)
#pragma unroll
        for (int r = 0; r < 4; r++)
          tb[(quad * 4 + r) * 136 + ni * 16 + col] =
              f2bf(fmaf(acc[mi][ni][r], sc, bns_[ni]));
      asm volatile("s_waitcnt lgkmcnt(0)" ::: "memory");
      __builtin_amdgcn_sched_barrier(0);
#pragma unroll
      for (int p = 0; p < 4; p++) {
        const int c   = p * 64 + lane;     // 256 chunks of 8 u16
        const int row = c >> 4;            // 0..15 (m-row within group)
        const int ch  = c & 15;            // 16 chunks per row
        u16x8 vv = *(const u16x8*)&tb[row * 136 + ch * 8];
        const int h  = h0 + (ch >> 3);
        const int dk = (ch & 7) * 8;
        const int s  = sB + mi * 16 + row;
        *(u16x8*)&((ushort_t*)Outv)[(((size_t)(b_ * NHEAD + h)) * SLEN + s) * DKH + dk] = vv;
      }
      asm volatile("s_waitcnt lgkmcnt(0)" ::: "memory");  // reads retire
      __builtin_amdgcn_sched_barrier(0);                  // before overwrite
    }
    return;
  }

#pragma unroll
  for (int ni = 0; ni < 8; ni++) {
    const int n  = n0 + wn + ni * 16 + col;
    const float bn = bias[n];
    const int h  = n >> 6, dk = n & (DKH - 1);
#pragma unroll
    for (int mi = 0; mi < 4; mi++) {
      if (mode == 2) {
        const int s0 = ((m0 + wm + mi * 16 + quad * 4) & (SLEN - 1));
        u16x4 pk;
#pragma unroll
        for (int r = 0; r < 4; r++) pk[r] = f2bf(acc[mi][ni][r] + bn);
        *(u16x4*)&((ushort_t*)Outv)[(((size_t)(b_ * NHEAD + h)) * DKH + dk) * SLEN + s0] = pk;
      } else {
#pragma unroll
        for (int r = 0; r < 4; r++) {
          const int m = m0 + wm + mi * 16 + quad * 4 + r;
          ((float*)Outv)[(size_t)m * DMODEL + n] = acc[mi][ni][r] + bn;
        }
      }
    }
  }
}

// fused Q/K/V projections (X = bf16 workspace, W = bf16 workspace)
__global__ __launch_bounds__(256, 3) void gemm_qkv(
    const ushort_t* Xq, const ushort_t* Xk, const ushort_t* Xv,
    const ushort_t* Wbf,
    const float* bq, const float* bk, const float* bv,
    ushort_t* Qh, ushort_t* Kh, ushort_t* VhT) {
  const int z = blockIdx.z;
  const ushort_t* X = (z == 0) ? Xq : (z == 1) ? Xk : Xv;
  const ushort_t* W = Wbf + ((size_t)z << 20);
  const float* bias = (z == 0) ? bq : (z == 1) ? bk : bv;
  ushort_t* out     = (z == 0) ? Qh : (z == 1) ? Kh : VhT;
  gemm_body(X, W, bias, out, (z == 2) ? 2 : 1, (z == 0) ? QSCALE : 1.0f);
}

__global__ __launch_bounds__(256, 3) void gemm_out(
    const ushort_t* X, const ushort_t* Wobf, const float* bo, float* Out) {
  gemm_body(X, Wobf, bo, Out, 0, 1.0f);
}

// ---------------------------------------------------------------------------
// Flash attention, causal. Paired q-blocks (x, 31-x): every workgroup does
// exactly 33 tile-computes (uniform load) and stages each K/V tile ONCE for
// the pair. Grid (16, 64) = 1024 blocks = 4/CU. Q pre-scaled by log2(e)/8
// in the projection; p = exp2(s) with no offset (constant factor cancels
// between PV numerator and row-sum denominator).
// ---------------------------------------------------------------------------
__global__ __launch_bounds__(256, 4) void flash_attn(
    const ushort_t* __restrict__ Qh, const ushort_t* __restrict__ Kh,
    const ushort_t* __restrict__ VhT, ushort_t* __restrict__ Out)
{
  __shared__ ushort_t lK[2 * 64 * 64];   // 16 KB (double-buffered)
  __shared__ ushort_t lV[2 * 64 * 64];   // 16 KB (double-buffered)
  __shared__ ushort_t lP[4 * 16 * 64];   //  8 KB

  const int t    = threadIdx.x;
  const int lane = t & 63;
  const int w    = t >> 6;
  const int col  = lane & 15;
  const int quad = lane >> 4;
  const int bh   = blockIdx.y;
  const int x    = blockIdx.x;          // 0..15
  const int ntA  = x + 1;               // tiles for q-block A
  const int ntB  = 32 - x;              // tiles for q-block B  (ntB > ntA)
  const int q0A  = x * 64;
  const int q0B  = (31 - x) * 64;

  const ushort_t* Qb = Qh  + (size_t)bh * SLEN * DKH;
  const ushort_t* Kb = Kh  + (size_t)bh * SLEN * DKH;
  const ushort_t* Vt = VhT + (size_t)bh * DKH * SLEN;

  bf16x8 qfA[2], qfB[2];
  {
    const int ra = q0A + w * 16 + col;
    const int rb = q0B + w * 16 + col;
    qfA[0] = __builtin_bit_cast(bf16x8, *(const u16x8*)&Qb[(size_t)ra * DKH + quad * 8]);
    qfA[1] = __builtin_bit_cast(bf16x8, *(const u16x8*)&Qb[(size_t)ra * DKH + 32 + quad * 8]);
    qfB[0] = __builtin_bit_cast(bf16x8, *(const u16x8*)&Qb[(size_t)rb * DKH + quad * 8]);
    qfB[1] = __builtin_bit_cast(bf16x8, *(const u16x8*)&Qb[(size_t)rb * DKH + 32 + quad * 8]);
  }

  f32x4 accA[4], accB[4], laccA, laccB;
#pragma unroll
  for (int n2 = 0; n2 < 4; n2++) {
    accA[n2] = f32x4{0.f, 0.f, 0.f, 0.f};
    accB[n2] = f32x4{0.f, 0.f, 0.f, 0.f};
  }
  laccA = f32x4{0.f, 0.f, 0.f, 0.f};
  laccB = f32x4{0.f, 0.f, 0.f, 0.f};

  u16x8 ones_u;
#pragma unroll
  for (int i = 0; i < 8; ++i) ones_u[i] = 0x3F80;  // bf16 1.0
  const bf16x8 onesf = __builtin_bit_cast(bf16x8, ones_u);

  const int fA   = t * 8;
  const int rowA = fA >> 6;
  const int innA = fA & 63;
  const int cA   = innA ^ ((rowA & 7) * 8);
  const int rowB = rowA + 32;
  const int cB   = innA ^ ((rowB & 7) * 8);
  const ushort_t* gK0 = Kb + (size_t)rowA * DKH + cA;
  const ushort_t* gK1 = Kb + (size_t)rowB * DKH + cB;
  const ushort_t* gV0 = Vt + (size_t)rowA * SLEN + cA;
  const ushort_t* gV1 = Vt + (size_t)rowB * SLEN + cB;
  ushort_t* sK0 = &lK[fA];
  ushort_t* sK1 = &lK[fA + 2048];
  ushort_t* sV0 = &lV[fA];
  ushort_t* sV1 = &lV[fA + 2048];

  ushort_t* lPw = &lP[w * 1024];

  // one tile-compute for one q-block: QK^T -> exp2 -> P (LDS) -> PV
  auto compute = [&](const bf16x8* qf, f32x4* acc_o, f32x4& lacc,
                     const int q0, const bool diag, const int kb,
                     const ushort_t* Kc, const ushort_t* Vc) {
    f32x4 sacc[4];
#pragma unroll
    for (int nt = 0; nt < 4; nt++) sacc[nt] = f32x4{0.f, 0.f, 0.f, 0.f};
#pragma unroll
    for (int ks = 0; ks < 2; ++ks) {
#pragma unroll
      for (int nt = 0; nt < 4; ++nt) {
        bf16x8 kf = __builtin_bit_cast(bf16x8,
            *(const u16x8*)&Kc[swz(nt * 16 + col, ks * 32 + quad * 8)]);
        sacc[nt] = __builtin_amdgcn_mfma_f32_16x16x32_bf16(qf[ks], kf, sacc[nt], 0, 0, 0);
      }
    }
#pragma unroll
    for (int r = 0; r < 4; r++) {
#pragma unroll
      for (int nt = 0; nt < 4; nt++) {
        float p = exp2f(sacc[nt][r]);
        if (diag) {
          const int kg = kb + nt * 16 + col;
          const int qg = q0 + w * 16 + quad * 4 + r;
          if (kg > qg) p = 0.f;
        }
        lPw[swz(quad * 4 + r, nt * 16 + col)] = f2bf(p);
      }
    }
    asm volatile("s_waitcnt lgkmcnt(0)" ::: "memory");
#pragma unroll
    for (int ks = 0; ks < 2; ++ks) {
      bf16x8 pf = __builtin_bit_cast(bf16x8,
          *(const u16x8*)&lPw[swz(col, ks * 32 + quad * 8)]);
      lacc = __builtin_amdgcn_mfma_f32_16x16x32_bf16(pf, onesf, lacc, 0, 0, 0);
#pragma unroll
      for (int n2 = 0; n2 < 4; ++n2) {
        bf16x8 vf = __builtin_bit_cast(bf16x8,
            *(const u16x8*)&Vc[swz(n2 * 16 + col, ks * 32 + quad * 8)]);
        acc_o[n2] = __builtin_amdgcn_mfma_f32_16x16x32_bf16(pf, vf, acc_o[n2], 0, 0, 0);
      }
    }
  };

  // prologue: stage tile 0 into buffer 0
  gld_lds16(gK0, sK0);
  gld_lds16(gK1, sK1);
  gld_lds16(gV0, sV0);
  gld_lds16(gV1, sV1);

  for (int it = 0; it < ntB; ++it) {
    const int cur = it & 1;
    const int kb  = it * 64;
    const ushort_t* Kc = &lK[cur * 4096];
    const ushort_t* Vc = &lV[cur * 4096];

    if (it + 1 < ntB) {
      const size_t kb1 = (size_t)(it + 1) * 64;
      const int nb = (cur ^ 1) * 4096;
      gld_lds16(gK0 + kb1 * DKH, sK0 + nb);
      gld_lds16(gK1 + kb1 * DKH, sK1 + nb);
      gld_lds16(gV0 + kb1,       sV0 + nb);
      gld_lds16(gV1 + kb1,       sV1 + nb);
      asm volatile("s_waitcnt vmcnt(4)" ::: "memory");
    } else {
      asm volatile("s_waitcnt vmcnt(0)" ::: "memory");
    }
    __builtin_amdgcn_s_barrier();   // current buffer fully landed, all waves

    compute(qfB, accB, laccB, q0B, it == ntB - 1, kb, Kc, Vc);
    if (it < ntA)
      compute(qfA, accA, laccA, q0A, it == ntA - 1, kb, Kc, Vc);

    __builtin_amdgcn_s_barrier();   // reads of buf[cur] done before re-stage
  }

  const int b_ = bh >> 4;
  const int h  = bh & (NHEAD - 1);
#pragma unroll
  for (int side = 0; side < 2; ++side) {
    const f32x4* ao = side ? accA : accB;
    const f32x4& la = side ? laccA : laccB;
    const int q0 = side ? q0A : q0B;
#pragma unroll
    for (int r = 0; r < 4; r++) {
      const int qg = q0 + w * 16 + quad * 4 + r;
      const float inv = 1.f / la[r];
#pragma unroll
      for (int n2 = 0; n2 < 4; n2++) {
        const size_t oidx = ((size_t)b_ * SLEN + qg) * DMODEL + h * DKH + n2 * 16 + col;
        Out[oidx] = f2bf(ao[n2][r] * inv);
      }
    }
  }
}

// ---------------------------------------------------------------------------
extern "C" void kernel_launch(void* const* d_in, const int* in_sizes, int n_in,
                              void* d_out, int out_size, void* d_ws, size_t ws_size,
                              hipStream_t stream) {
  (void)in_sizes; (void)n_in; (void)out_size; (void)ws_size;
  const float* q  = (const float*)d_in[0];
  const float* k  = (const float*)d_in[1];
  const float* v  = (const float*)d_in[2];
  const float* Wq = (const float*)d_in[3];
  const float* bq = (const float*)d_in[4];
  const float* Wk = (const float*)d_in[5];
  const float* bk = (const float*)d_in[6];
  const float* Wv = (const float*)d_in[7];
  const float* bv = (const float*)d_in[8];
  const float* Wo = (const float*)d_in[9];
  const float* bo = (const float*)d_in[10];
  // d_in[11] = causal mask (applied analytically)

  ushort_t* ws = (ushort_t*)d_ws;
  const size_t NELEM = (size_t)BATCH * SLEN * DMODEL;   // 8M elems
  ushort_t* Wbf = ws;                        // 4 x 1M bf16 (Wq,Wk,Wv,Wo)  8 MB
  ushort_t* Qh  = ws + 4 * (1u << 20);       // [B,H,S,DK] bf16           16 MB
  ushort_t* Kh  = Qh + NELEM;                // [B,H,S,DK] bf16           16 MB
  ushort_t* Xq  = Kh + NELEM;                // [B,S,D] bf16 (q)          16 MB
  ushort_t* Xk  = Xq + NELEM;                // [B,S,D] bf16 (k)          16 MB
  ushort_t* Ao  = Xq;                        // aliases Xq (dead after qkv)
  ushort_t* VhT = (ushort_t*)d_out;          // [B,H,DK,S] bf16 in d_out lo half
  ushort_t* Xv  = (ushort_t*)d_out + NELEM;  // [B,S,D] bf16 (v) in d_out hi half
                                             // (both dead before gemm_out writes)

  hipLaunchKernelGGL(cvt_all, dim3(2048 + 12288), dim3(256), 0, stream,
                     Wq, Wk, Wv, Wo, q, k, v, Wbf, Xq, Xk, Xv);
  hipLaunchKernelGGL(gemm_qkv, dim3(64, 4, 3), dim3(256), 0, stream,
                     Xq, Xk, Xv, Wbf, bq, bk, bv, Qh, Kh, VhT);
  hipLaunchKernelGGL(flash_attn, dim3(16, BATCH * NHEAD), dim3(256), 0, stream,
                     Qh, Kh, VhT, Ao);
  hipLaunchKernelGGL(gemm_out, dim3(64, 4), dim3(256), 0, stream,
                     Ao, Wbf + (3u << 20), bo, (float*)d_out);
}